// Round 10
// baseline (139.964 us; speedup 1.0000x reference)
//
#include <hip/hip_runtime.h>
#include <stdint.h>

#define N_PTS 256

typedef float v2f __attribute__((ext_vector_type(2)));

__device__ __forceinline__ unsigned xmax(unsigned a, unsigned b) { return a > b ? a : b; }

// Fused single-inst DPP max stage (old=0 + bound_ctrl=1 = unsigned-max identity;
// fusion verified R7 via VALUBusy drop).
template<int CTRL>
__device__ __forceinline__ unsigned dppmax(unsigned x) {
    unsigned y = (unsigned)__builtin_amdgcn_update_dpp(0, (int)x, CTRL, 0xf, 0xf, true);
    return xmax(x, y);
}

// FULL-BROADCAST wave64 max: every lane ends with the max over all 64 lanes.
// Butterfly: xor1,xor2 (quad_perm), 8/16 (mirrors: exact for idempotent max),
// xor16 (ds_swizzle bit-mode), xor32 (ds_bpermute crossbar). No readlane, no
// ballot, no SALU -> zero vector->scalar pipeline-drain crossings.
__device__ __forceinline__ unsigned bcast_max64(unsigned c, int bp_addr) {
    c = dppmax<0xB1>(c);   // quad_perm [1,0,3,2]  : xor1
    c = dppmax<0x4E>(c);   // quad_perm [2,3,0,1]  : xor2
    c = dppmax<0x141>(c);  // row_half_mirror      : combine 4s -> 8
    c = dppmax<0x140>(c);  // row_mirror           : combine 8s -> 16
    c = xmax(c, (unsigned)__builtin_amdgcn_ds_swizzle((int)c, 0x401F)); // xor16 -> 32
    c = xmax(c, (unsigned)__builtin_amdgcn_ds_bpermute(bp_addr, (int)c)); // xor32 -> 64
    return c;
}

// One greedy round, entirely in the vector domain (complement-uint min trick,
// bit-exact vs fp32 numpy ref -- validated absmax 0.0 since R1).
__device__ __forceinline__ void round1(
    float tjx, float tjy, float& acc,
    v2f& p0, v2f& p1, v2f& p2, v2f& p3,
    unsigned vL0, unsigned vL1, unsigned vL2, unsigned vL3,
    unsigned vK0, unsigned vK1, unsigned vK2, unsigned vK3,
    int bp_addr, float vNAN)
{
    #pragma clang fp contract(off)
    v2f t; t.x = tjx; t.y = tjy;
    v2f q0 = t - p0, q1 = t - p1, q2 = t - p2, q3 = t - p3;
    v2f s0 = q0 * q0, s1 = q1 * q1, s2 = q2 * q2, s3 = q3 * q3;
    float d0 = s0.x + s0.y;
    float d1 = s1.x + s1.y;
    float d2 = s2.x + s2.y;
    float d3 = s3.x + s3.y;

    // per-lane min (NaN = used, dropped by v_min_f32), then broadcast wave min
    float m = fminf(fminf(d0, d1), fminf(d2, d3));
    unsigned cmax = bcast_max64(~__float_as_uint(m), bp_addr);
    unsigned mu = ~cmax;  // min bits, in EVERY lane

    // per-lane key: lowest achieving slot (slot-major), complement encoding.
    // max over ~(candidate index) = smallest index = exact first-min-wins.
    // Non-achievers contribute 0 (the max identity). NaN bits never equal mu.
    unsigned u = (__float_as_uint(d0) == mu) ? vK0
               : (__float_as_uint(d1) == mu) ? vK1
               : (__float_as_uint(d2) == mu) ? vK2
               : (__float_as_uint(d3) == mu) ? vK3
               : 0u;
    unsigned k = ~bcast_max64(u, bp_addr);  // global argmin index, every lane

    // se = min(m, BIG); if !(m < BIG), k = 0 (uint cmp == float cmp, m >= +0)
    const unsigned BIG_U = __float_as_uint(66049.0f);  // 257^2
    k = (mu < BIG_U) ? k : 0u;                         // v_cmp + v_cndmask
    unsigned se = (mu < BIG_U) ? mu : BIG_U;           // v_min_u32
    acc += __uint_as_float(se);                        // uniform across lanes

    // poison candidate k: k == s*64+lane identifies owning lane+slot directly
    p0.x = (k == vL0) ? vNAN : p0.x;
    p1.x = (k == vL1) ? vNAN : p1.x;
    p2.x = (k == vL2) ? vNAN : p2.x;
    p3.x = (k == vL3) ? vNAN : p3.x;
}

__device__ __forceinline__ void phase(
    float txc, float tyc, float& acc,
    v2f& p0, v2f& p1, v2f& p2, v2f& p3,
    unsigned vL0, unsigned vL1, unsigned vL2, unsigned vL3,
    unsigned vK0, unsigned vK1, unsigned vK2, unsigned vK3,
    int bp_addr, float vNAN)
{
    #pragma unroll 1
    for (int j = 0; j < 64; ++j) {
        // target broadcast: readlane -> SGPR consumed by VALU only (no SALU)
        float tjx = __int_as_float(__builtin_amdgcn_readlane(__float_as_int(txc), j));
        float tjy = __int_as_float(__builtin_amdgcn_readlane(__float_as_int(tyc), j));
        round1(tjx, tjy, acc, p0, p1, p2, p3,
               vL0, vL1, vL2, vL3, vK0, vK1, vK2, vK3, bp_addr, vNAN);
    }
}

// One wave per batch, 2 waves/SIMD (B=2048-capped; R5: 1 wave/SIMD is 2x worse).
__global__ __launch_bounds__(256) void greedy_match_kernel(
    const float* __restrict__ input,
    const float* __restrict__ targets,
    float* __restrict__ out,
    int B, float scale)
{
    __shared__ float wsum[4];
    const unsigned lane = threadIdx.x & 63;
    const int wid  = threadIdx.x >> 6;
    const int b    = blockIdx.x * 4 + wid;

    float acc = 0.0f;
    if (b < B) {
        const v2f* pin = (const v2f*)(input   + (size_t)b * (2 * N_PTS));
        const v2f* ptg = (const v2f*)(targets + (size_t)b * (2 * N_PTS));

        v2f p0 = pin[lane],       p1 = pin[64 + lane];
        v2f p2 = pin[128 + lane], p3 = pin[192 + lane];
        v2f t0 = ptg[lane],       t1 = ptg[64 + lane];
        v2f t2 = ptg[128 + lane], t3 = ptg[192 + lane];

        // loop-invariant per-lane constants (VGPRs)
        const unsigned vL0 = lane,        vL1 = lane | 64u;
        const unsigned vL2 = lane | 128u, vL3 = lane | 192u;
        const unsigned vK0 = ~vL0, vK1 = ~vL1, vK2 = ~vL2, vK3 = ~vL3;
        const int bp_addr = (int)((lane ^ 32u) << 2);  // ds_bpermute byte addr
        const float vNAN = __int_as_float(0x7fc00000);

        phase(t0.x, t0.y, acc, p0, p1, p2, p3, vL0, vL1, vL2, vL3,
              vK0, vK1, vK2, vK3, bp_addr, vNAN);
        phase(t1.x, t1.y, acc, p0, p1, p2, p3, vL0, vL1, vL2, vL3,
              vK0, vK1, vK2, vK3, bp_addr, vNAN);
        phase(t2.x, t2.y, acc, p0, p1, p2, p3, vL0, vL1, vL2, vL3,
              vK0, vK1, vK2, vK3, bp_addr, vNAN);
        phase(t3.x, t3.y, acc, p0, p1, p2, p3, vL0, vL1, vL2, vL3,
              vK0, vK1, vK2, vK3, bp_addr, vNAN);
    }

    if (lane == 0) wsum[wid] = acc;
    __syncthreads();
    if (threadIdx.x == 0) {
        float s = (wsum[0] + wsum[1] + wsum[2] + wsum[3]) * scale;
        atomicAdd(out, s);
    }
}

extern "C" void kernel_launch(void* const* d_in, const int* in_sizes, int n_in,
                              void* d_out, int out_size, void* d_ws, size_t ws_size,
                              hipStream_t stream) {
    const float* input   = (const float*)d_in[0];
    const float* targets = (const float*)d_in[1];
    float* out = (float*)d_out;

    const int B = in_sizes[0] / (2 * N_PTS);
    const float scale = 1.0f / ((float)B * (float)(2 * N_PTS));

    // d_out is poisoned 0xAA before every call — zero it (graph-capturable).
    hipMemsetAsync(d_out, 0, sizeof(float) * (size_t)out_size, stream);

    const int blocks = (B + 3) / 4;  // 4 waves (4 batches) per 256-thread block
    greedy_match_kernel<<<blocks, 256, 0, stream>>>(input, targets, out, B, scale);
}

// Round 11
// 118.478 us; speedup vs baseline: 1.1813x; 1.1813x over previous
//
#include <hip/hip_runtime.h>
#include <stdint.h>

#define N_PTS 256

typedef unsigned long long ull;
typedef float v2f __attribute__((ext_vector_type(2)));

__device__ __forceinline__ unsigned umin2(unsigned a, unsigned b) { return a < b ? a : b; }

// Single-inst DPP max stage (old=0 + bound_ctrl=1 = unsigned-max identity ->
// GCNDPPCombine folds to one v_max_u32_dpp; verified R7).
template<int CTRL>
__device__ __forceinline__ unsigned dppmax(unsigned x) {
    unsigned y = (unsigned)__builtin_amdgcn_update_dpp(0, (int)x, CTRL, 0xf, 0xf, true);
    return x > y ? x : y;
}

// Wave MIN of non-negative fp32 via complemented unsigned MAX (bit-exact;
// NaN complements below all live values -> used candidates never win).
__device__ __forceinline__ unsigned wave_cmax(float m) {
    unsigned c = ~__float_as_uint(m);
    c = dppmax<0x121>(c); // row_ror:1
    c = dppmax<0x122>(c); // row_ror:2
    c = dppmax<0x124>(c); // row_ror:4
    c = dppmax<0x128>(c); // row_ror:8
    c = dppmax<0x142>(c); // row_bcast:15
    c = dppmax<0x143>(c); // row_bcast:31
    return ~((unsigned)__builtin_amdgcn_readlane((int)c, 63)); // SGPR, = min bits
}

__device__ __forceinline__ void round1(
    float tjx, float tjy, unsigned lane, float& acc,
    v2f& p0, v2f& p1, v2f& p2, v2f& p3, float vNAN)
{
    #pragma clang fp contract(off)
    v2f t; t.x = tjx; t.y = tjy;
    v2f q0 = t - p0, q1 = t - p1, q2 = t - p2, q3 = t - p3;
    v2f s0 = q0 * q0, s1 = q1 * q1, s2 = q2 * q2, s3 = q3 * q3;
    float d0 = s0.x + s0.y;
    float d1 = s1.x + s1.y;
    float d2 = s2.x + s2.y;
    float d3 = s3.x + s3.y;

    float m = fminf(fminf(d0, d1), fminf(d2, d3));
    unsigned mu = wave_cmax(m);
    float ms = __uint_as_float(mu);

    // exact first-min-wins argmin (slot-major): 4 ballots + flat SALU tree.
    ull e0 = __ballot(d0 == ms);
    ull e1 = __ballot(d1 == ms);
    ull e2 = __ballot(d2 == ms);
    ull e3 = __ballot(d3 == ms);
    unsigned u0 = (unsigned)(__ffsll((long long)e0) - 1);
    unsigned u1 = ((unsigned)(__ffsll((long long)e1) - 1)) | 64u;
    unsigned u2 = ((unsigned)(__ffsll((long long)e2) - 1)) | 128u;
    unsigned u3 = ((unsigned)(__ffsll((long long)e3) - 1)) | 192u;
    unsigned k  = umin2(umin2(u0, u1), umin2(u2, u3));

    const unsigned BIG_U = __float_as_uint(66049.0f); // 257^2
    bool ok = (mu < BIG_U);
    k = ok ? k : 0u;                 // s_cselect
    unsigned se = umin2(mu, BIG_U);  // s_min_u32
    acc += __uint_as_float(se);      // v_add_f32, SGPR src

    unsigned ks = k >> 6, kl = k & 63u;
    bool hit = (lane == kl);         // v_cmp -> vcc
    p0.x = (hit && ks == 0) ? vNAN : p0.x;
    p1.x = (hit && ks == 1) ? vNAN : p1.x;
    p2.x = (hit && ks == 2) ? vNAN : p2.x;
    p3.x = (hit && ks == 3) ? vNAN : p3.x;
}

__device__ __forceinline__ void phase(
    float txc, float tyc, unsigned lane, float& acc,
    v2f& p0, v2f& p1, v2f& p2, v2f& p3, float vNAN)
{
    #pragma unroll 4
    for (int j = 0; j < 64; ++j) {
        float tjx = __int_as_float(__builtin_amdgcn_readlane(__float_as_int(txc), j));
        float tjy = __int_as_float(__builtin_amdgcn_readlane(__float_as_int(tyc), j));
        round1(tjx, tjy, lane, acc, p0, p1, p2, p3, vNAN);
    }
}

// One wave per batch, 2 waves/SIMD. __launch_bounds__(256, 2): min 2 waves/EU
// -> 256-VGPR budget per wave. The bare (256) form let the compiler target
// 8 waves/EU (64-VGPR budget) and SPILL the candidate/target state to scratch
// -- the ~480 cyc/round of cache-latency stalls that made R1-R10's
// instruction-level changes all neutral (VGPR_Count 16-28 was the tell).
__global__ __launch_bounds__(256, 2) void greedy_match_kernel(
    const float* __restrict__ input,
    const float* __restrict__ targets,
    float* __restrict__ out,
    int B, float scale)
{
    __shared__ float wsum[4];
    const unsigned lane = threadIdx.x & 63;
    const int wid  = threadIdx.x >> 6;
    const int b    = blockIdx.x * 4 + wid;

    float acc = 0.0f;
    if (b < B) {
        const v2f* pin = (const v2f*)(input   + (size_t)b * (2 * N_PTS));
        const v2f* ptg = (const v2f*)(targets + (size_t)b * (2 * N_PTS));

        v2f p0 = pin[lane],       p1 = pin[64 + lane];
        v2f p2 = pin[128 + lane], p3 = pin[192 + lane];
        v2f t0 = ptg[lane],       t1 = ptg[64 + lane];
        v2f t2 = ptg[128 + lane], t3 = ptg[192 + lane];

        const float vNAN = __int_as_float(0x7fc00000);

        phase(t0.x, t0.y, lane, acc, p0, p1, p2, p3, vNAN);
        phase(t1.x, t1.y, lane, acc, p0, p1, p2, p3, vNAN);
        phase(t2.x, t2.y, lane, acc, p0, p1, p2, p3, vNAN);
        phase(t3.x, t3.y, lane, acc, p0, p1, p2, p3, vNAN);
    }

    if (lane == 0) wsum[wid] = acc;
    __syncthreads();
    if (threadIdx.x == 0) {
        float s = (wsum[0] + wsum[1] + wsum[2] + wsum[3]) * scale;
        atomicAdd(out, s);
    }
}

extern "C" void kernel_launch(void* const* d_in, const int* in_sizes, int n_in,
                              void* d_out, int out_size, void* d_ws, size_t ws_size,
                              hipStream_t stream) {
    const float* input   = (const float*)d_in[0];
    const float* targets = (const float*)d_in[1];
    float* out = (float*)d_out;

    const int B = in_sizes[0] / (2 * N_PTS);
    const float scale = 1.0f / ((float)B * (float)(2 * N_PTS));

    // d_out is poisoned 0xAA before every call — zero it (graph-capturable).
    hipMemsetAsync(d_out, 0, sizeof(float) * (size_t)out_size, stream);

    const int blocks = (B + 3) / 4;  // 4 waves (4 batches) per 256-thread block
    greedy_match_kernel<<<blocks, 256, 0, stream>>>(input, targets, out, B, scale);
}